// Round 2
// baseline (209.488 us; speedup 1.0000x reference)
//
#include <hip/hip_runtime.h>
#include <hip/hip_cooperative_groups.h>

namespace cg = cooperative_groups;

#define NB 32
#define NC 64
#define HW 25600          // 160*160
#define HW4 6400          // HW/4 (float4 per image)
#define BLKS_PER_B 25     // HW4 / 256
#define NBLOCKS 800       // NB * BLKS_PER_B
#define BN_EPS 1e-5f
#define LEAKY 0.1f

// Single fused cooperative kernel:
//   phase 1: mask accumulator in registers, per-block (sum,sumsq) -> partials
//   grid sync
//   phase 2: every block redundantly reduces partials (fixed order, bitwise
//            identical across blocks), applies BN + LeakyReLU, writes d_out.
__global__ __launch_bounds__(256) void maskgen_fused(
    const float* __restrict__ feats, const float* __restrict__ sf,
    const float* __restrict__ bn_w, const float* __restrict__ bn_b,
    float* __restrict__ out, float* __restrict__ partials) {
    const int b = blockIdx.x / BLKS_PER_B;
    const int t = (blockIdx.x % BLKS_PER_B) * 256 + threadIdx.x;  // float4 idx in image

    __shared__ float s_sf[NC];
    __shared__ float s_red[8];
    __shared__ double s_dred[8];

    if (threadIdx.x < NC) s_sf[threadIdx.x] = sf[b * NC + threadIdx.x];
    __syncthreads();

    // ---- phase 1: channel dot product, accumulator stays in registers ----
    const float4* f4 = reinterpret_cast<const float4*>(feats) + (size_t)b * NC * HW4 + t;
    float4 acc = make_float4(0.f, 0.f, 0.f, 0.f);
#pragma unroll 8
    for (int c = 0; c < NC; ++c) {
        float4 v = f4[(size_t)c * HW4];
        float s = s_sf[c];
        acc.x = fmaf(v.x, s, acc.x);
        acc.y = fmaf(v.y, s, acc.y);
        acc.z = fmaf(v.z, s, acc.z);
        acc.w = fmaf(v.w, s, acc.w);
    }

    float lsum = (acc.x + acc.y) + (acc.z + acc.w);
    float lsq  = acc.x * acc.x + acc.y * acc.y + acc.z * acc.z + acc.w * acc.w;
#pragma unroll
    for (int off = 32; off > 0; off >>= 1) {
        lsum += __shfl_down(lsum, off, 64);
        lsq  += __shfl_down(lsq,  off, 64);
    }
    const int wave = threadIdx.x >> 6;
    if ((threadIdx.x & 63) == 0) { s_red[wave] = lsum; s_red[4 + wave] = lsq; }
    __syncthreads();
    if (threadIdx.x == 0) {
        partials[blockIdx.x]           = (s_red[0] + s_red[1]) + (s_red[2] + s_red[3]);
        partials[NBLOCKS + blockIdx.x] = (s_red[4] + s_red[5]) + (s_red[6] + s_red[7]);
    }
    __threadfence();  // device-scope: partials visible across XCDs

    cg::this_grid().sync();

    // ---- phase 2: redundant per-block reduction of 800 partials (L2-hot) ----
    double s = 0.0, q = 0.0;
    for (int i = threadIdx.x; i < NBLOCKS; i += 256) {
        s += (double)partials[i];
        q += (double)partials[NBLOCKS + i];
    }
#pragma unroll
    for (int off = 32; off > 0; off >>= 1) {
        s += __shfl_down(s, off, 64);
        q += __shfl_down(q, off, 64);
    }
    if ((threadIdx.x & 63) == 0) { s_dred[wave] = s; s_dred[4 + wave] = q; }
    __syncthreads();

    const double S = (s_dred[0] + s_dred[1]) + (s_dred[2] + s_dred[3]);
    const double Q = (s_dred[4] + s_dred[5]) + (s_dred[6] + s_dred[7]);
    const double N = (double)NB * (double)HW;
    const double mean = S / N;
    const double var  = Q / N - mean * mean;
    const float inv   = rsqrtf((float)var + BN_EPS);
    const float scale = inv * bn_w[0];
    const float shift = bn_b[0] - (float)mean * scale;

    float4 r;
    r.x = fmaf(acc.x, scale, shift); r.x = (r.x >= 0.f) ? r.x : LEAKY * r.x;
    r.y = fmaf(acc.y, scale, shift); r.y = (r.y >= 0.f) ? r.y : LEAKY * r.y;
    r.z = fmaf(acc.z, scale, shift); r.z = (r.z >= 0.f) ? r.z : LEAKY * r.z;
    r.w = fmaf(acc.w, scale, shift); r.w = (r.w >= 0.f) ? r.w : LEAKY * r.w;
    reinterpret_cast<float4*>(out)[(size_t)b * HW4 + t] = r;
}

extern "C" void kernel_launch(void* const* d_in, const int* in_sizes, int n_in,
                              void* d_out, int out_size, void* d_ws, size_t ws_size,
                              hipStream_t stream) {
    const float* sf    = (const float*)d_in[0];   // [32,64,1,1]
    const float* feats = (const float*)d_in[1];   // [32,64,160,160]
    const float* bn_w  = (const float*)d_in[2];   // [1]
    const float* bn_b  = (const float*)d_in[3];   // [1]
    float* out      = (float*)d_out;              // [32,1,160,160] fp32
    float* partials = (float*)d_ws;               // 2*800 floats

    void* args[] = {(void*)&feats, (void*)&sf, (void*)&bn_w, (void*)&bn_b,
                    (void*)&out, (void*)&partials};
    hipLaunchCooperativeKernel((const void*)maskgen_fused, dim3(NBLOCKS), dim3(256),
                               args, 0, stream);
}

// Round 3
// 41.436 us; speedup vs baseline: 5.0558x; 5.0558x over previous
//
#include <hip/hip_runtime.h>

#define NB 32
#define NC 64
#define HW 25600          // 160*160
#define HW4 6400          // HW/4 (float4 per image)
#define BLKS_PER_B 25     // HW4 / 256
#define NBLOCKS 800       // NB * BLKS_PER_B
#define BN_EPS 1e-5f
#define LEAKY 0.1f

// Pass 1: mask = einsum('bchw,bc->bhw') -> d_out; per-block (sum, sumsq) partials.
__global__ __launch_bounds__(256) void maskgen_pass1(
    const float* __restrict__ feats, const float* __restrict__ sf,
    float* __restrict__ mask, float* __restrict__ partials) {
    const int b = blockIdx.x / BLKS_PER_B;
    const int t = (blockIdx.x % BLKS_PER_B) * 256 + threadIdx.x;  // float4 idx within image

    __shared__ float s_sf[NC];
    if (threadIdx.x < NC) s_sf[threadIdx.x] = sf[b * NC + threadIdx.x];
    __syncthreads();

    const float4* f4 = reinterpret_cast<const float4*>(feats) + (size_t)b * NC * HW4 + t;
    float4 acc = make_float4(0.f, 0.f, 0.f, 0.f);
#pragma unroll 16
    for (int c = 0; c < NC; ++c) {
        float4 v = f4[(size_t)c * HW4];
        float s = s_sf[c];
        acc.x = fmaf(v.x, s, acc.x);
        acc.y = fmaf(v.y, s, acc.y);
        acc.z = fmaf(v.z, s, acc.z);
        acc.w = fmaf(v.w, s, acc.w);
    }
    reinterpret_cast<float4*>(mask)[(size_t)b * HW4 + t] = acc;

    float lsum = (acc.x + acc.y) + (acc.z + acc.w);
    float lsq  = acc.x * acc.x + acc.y * acc.y + acc.z * acc.z + acc.w * acc.w;
#pragma unroll
    for (int off = 32; off > 0; off >>= 1) {
        lsum += __shfl_down(lsum, off, 64);
        lsq  += __shfl_down(lsq,  off, 64);
    }
    __shared__ float s_red[8];
    const int wave = threadIdx.x >> 6;
    if ((threadIdx.x & 63) == 0) { s_red[wave] = lsum; s_red[4 + wave] = lsq; }
    __syncthreads();
    if (threadIdx.x == 0) {
        partials[blockIdx.x]           = (s_red[0] + s_red[1]) + (s_red[2] + s_red[3]);
        partials[NBLOCKS + blockIdx.x] = (s_red[4] + s_red[5]) + (s_red[6] + s_red[7]);
    }
}

// Pass 2 (fused stats + apply): every block redundantly reduces the 800
// partials (fixed order -> identical result in all blocks, deterministic),
// then applies BN + LeakyReLU to its slice of the mask in-place.
__global__ __launch_bounds__(256) void maskgen_pass2(
    float* __restrict__ mask, const float* __restrict__ partials,
    const float* __restrict__ bn_w, const float* __restrict__ bn_b) {
    double s = 0.0, q = 0.0;
    for (int i = threadIdx.x; i < NBLOCKS; i += 256) {
        s += (double)partials[i];
        q += (double)partials[NBLOCKS + i];
    }
#pragma unroll
    for (int off = 32; off > 0; off >>= 1) {
        s += __shfl_down(s, off, 64);
        q += __shfl_down(q, off, 64);
    }
    __shared__ double sh[8];
    const int wave = threadIdx.x >> 6;
    if ((threadIdx.x & 63) == 0) { sh[wave] = s; sh[4 + wave] = q; }
    __syncthreads();

    const double S = (sh[0] + sh[1]) + (sh[2] + sh[3]);
    const double Q = (sh[4] + sh[5]) + (sh[6] + sh[7]);
    const double N = (double)NB * (double)HW;
    const double mean = S / N;
    const double var  = Q / N - mean * mean;
    const float inv   = rsqrtf((float)var + BN_EPS);
    const float scale = inv * bn_w[0];
    const float shift = bn_b[0] - (float)mean * scale;

    const int i = blockIdx.x * 256 + threadIdx.x;  // float4 idx, grid = NB*HW4/256
    float4 v = reinterpret_cast<float4*>(mask)[i];
    float4 r;
    r.x = fmaf(v.x, scale, shift); r.x = (r.x >= 0.f) ? r.x : LEAKY * r.x;
    r.y = fmaf(v.y, scale, shift); r.y = (r.y >= 0.f) ? r.y : LEAKY * r.y;
    r.z = fmaf(v.z, scale, shift); r.z = (r.z >= 0.f) ? r.z : LEAKY * r.z;
    r.w = fmaf(v.w, scale, shift); r.w = (r.w >= 0.f) ? r.w : LEAKY * r.w;
    reinterpret_cast<float4*>(mask)[i] = r;
}

extern "C" void kernel_launch(void* const* d_in, const int* in_sizes, int n_in,
                              void* d_out, int out_size, void* d_ws, size_t ws_size,
                              hipStream_t stream) {
    const float* sf    = (const float*)d_in[0];   // [32,64,1,1]
    const float* feats = (const float*)d_in[1];   // [32,64,160,160]
    const float* bn_w  = (const float*)d_in[2];   // [1]
    const float* bn_b  = (const float*)d_in[3];   // [1]
    float* out      = (float*)d_out;              // [32,1,160,160] fp32
    float* partials = (float*)d_ws;               // 2*800 floats

    maskgen_pass1<<<NBLOCKS, 256, 0, stream>>>(feats, sf, out, partials);
    maskgen_pass2<<<NBLOCKS, 256, 0, stream>>>(out, partials, bn_w, bn_b);
}